// Round 21
// baseline (376.311 us; speedup 1.0000x reference)
//
#include <hip/hip_runtime.h>

#define EPSF 1e-6f

// Shapes: B=4, S=4096, H=8, D=128;  BS = 16384 rows; channels = 4096
// r20-proven state + fusion: k_ln_gates+k_scan_a -> k_ln_gates_scan (one block per
// 64-row scan chunk; chunk (F,C) products computed from bf16-rounded gates, bit-identical).
// GEMM: BK=64 double-buffered (64KB, 2 blocks/CU), counted vmcnt(4), planar A, scalar epilogue.

typedef __attribute__((ext_vector_type(8))) short short8v;
typedef __attribute__((ext_vector_type(4))) float float4v;

__device__ __forceinline__ float sigm(float x) { return 1.0f / (1.0f + __expf(-x)); }

__device__ __forceinline__ unsigned short f2bf(float f) {
    unsigned int u = __float_as_uint(f);
    u = (u + 0x7fffu + ((u >> 16) & 1u)) >> 16;   // RNE
    return (unsigned short)u;
}
__device__ __forceinline__ float bf2f(unsigned short s) { return __uint_as_float(((unsigned int)s) << 16); }
__device__ __forceinline__ float bf2f_lo(unsigned int p) { return __uint_as_float(p << 16); }
__device__ __forceinline__ float bf2f_hi(unsigned int p) { return __uint_as_float(p & 0xffff0000u); }
__device__ __forceinline__ unsigned int pack2bf(float a, float b) {
    return (unsigned int)f2bf(a) | ((unsigned int)f2bf(b) << 16);
}

__device__ __forceinline__ void block_reduce2(float& a, float& b) {
#pragma unroll
    for (int off = 32; off > 0; off >>= 1) {
        a += __shfl_down(a, off);
        b += __shfl_down(b, off);
    }
    __shared__ float sa[8], sb[8];
    int wid = threadIdx.x >> 6;
    int lane = threadIdx.x & 63;
    if (lane == 0) { sa[wid] = a; sb[wid] = b; }
    __syncthreads();
    a = sa[0] + sa[1] + sa[2] + sa[3];
    b = sb[0] + sb[1] + sb[2] + sb[3];
}

// ---- W transpose+cast for BOTH weights in one launch ----
__global__ __launch_bounds__(256) void k_prep_w(const float* __restrict__ Wh, const float* __restrict__ Wo,
                                                unsigned short* __restrict__ WTH,
                                                unsigned short* __restrict__ WTO) {
    int idx = blockIdx.x * 256 + threadIdx.x;    // 1,048,576 total
    if (idx < 786432) {
        int k = idx & 255;
        int rest = idx >> 8;                      // h*384 + o
        int o = rest % 384;
        int h = rest / 384;
        WTH[idx] = f2bf(Wh[((size_t)h * 256 + k) * 384 + o]);
    } else {
        int i2 = idx - 786432;
        int k = i2 & 255;
        int rest = i2 >> 8;                       // h*128 + o
        int o = rest & 127;
        int h = rest >> 7;
        WTO[i2] = f2bf(Wo[((size_t)h * 256 + k) * 128 + o]);
    }
}

// ---- cumsum pass A: chunk sums + emit XB (planar [h][bs][d]) ----
__global__ __launch_bounds__(256) void k_cumsum_a(const float* __restrict__ X, float* __restrict__ cS,
                                                  unsigned short* __restrict__ XB) {
    int t = blockIdx.x * 256 + threadIdx.x;          // 262144
    int d = t & 127, h = (t >> 7) & 7, k = (t >> 10) & 63, b = t >> 16;
    size_t xbase = (((size_t)(b * 4096 + k * 64)) * 8 + h) * 128 + d;          // X interleaved
    size_t pbase = ((size_t)h * 16384 + b * 4096 + k * 64) * 128 + d;           // XB planar
    float s = 0.f;
    for (int j = 0; j < 64; ++j) {
        unsigned short xb = f2bf(X[xbase + (size_t)j * 1024]);
        XB[pbase + (size_t)j * 128] = xb;
        s += bf2f(xb);
    }
    cS[(size_t)((b * 8 + h) * 128 + d) * 64 + k] = s;
}

// pass B: per-channel exclusive scan of chunk sums; one wave per channel
__global__ __launch_bounds__(256) void k_cumsum_b(const float* __restrict__ cS, float* __restrict__ cO) {
    int wave = (blockIdx.x * 256 + threadIdx.x) >> 6;   // 4096 waves
    int lane = threadIdx.x & 63;
    size_t idx = (size_t)wave * 64 + lane;
    float v = cS[idx];
    float incl = v;
#pragma unroll
    for (int d = 1; d < 64; d <<= 1) {
        float t = __shfl_up(incl, d);
        if (lane >= d) incl += t;
    }
    cO[idx] = incl - v;
}

// pass C: exclusive prefix from XB (planar), stored bf16 planar
__global__ __launch_bounds__(256) void k_cumsum_c(const unsigned short* __restrict__ XB,
                                                  const float* __restrict__ cO,
                                                  unsigned short* __restrict__ CSUMB) {
    int t = blockIdx.x * 256 + threadIdx.x;
    int d = t & 127, h = (t >> 7) & 7, k = (t >> 10) & 63, b = t >> 16;
    int ch = (b * 8 + h) * 128 + d;
    float run = cO[(size_t)ch * 64 + k];
    size_t pbase = ((size_t)h * 16384 + b * 4096 + k * 64) * 128 + d;
    for (int j = 0; j < 64; ++j) {
        float x = bf2f(XB[pbase + (size_t)j * 128]);
        CSUMB[pbase + (size_t)j * 128] = f2bf(run);
        run += x;
    }
}

// ---- LN over (h,d) per (b,s): planar bf16 in, planar bf16 out ----
__global__ __launch_bounds__(256) void k_ln_csum(const unsigned short* __restrict__ CSUMB,
                                                 unsigned short* __restrict__ CSB,
                                                 const float* __restrict__ g, const float* __restrict__ bb) {
    int bs = blockIdx.x, t = threadIdx.x;
    int h = t >> 5, c = t & 31;
    size_t u2i = ((size_t)h * 16384 + bs) * 32 + c;    // uint2 index into planar array
    uint2 u = ((const uint2*)CSUMB)[u2i];
    float4 v;
    v.x = bf2f_lo(u.x); v.y = bf2f_hi(u.x);
    v.z = bf2f_lo(u.y); v.w = bf2f_hi(u.y);
    float s = v.x + v.y + v.z + v.w;
    float ss = v.x * v.x + v.y * v.y + v.z * v.z + v.w * v.w;
    block_reduce2(s, ss);
    float m = s * (1.f / 1024.f);
    float var = ss * (1.f / 1024.f) - m * m;
    float r = rsqrtf(fmaxf(var, 0.f) + EPSF);
    float4 gv = ((const float4*)g)[t];
    float4 bv = ((const float4*)bb)[t];
    uint2 o;
    o.x = pack2bf((v.x - m) * r * gv.x + bv.x, (v.y - m) * r * gv.y + bv.y);
    o.y = pack2bf((v.z - m) * r * gv.z + bv.z, (v.w - m) * r * gv.w + bv.w);
    ((uint2*)CSB)[u2i] = o;
}

// ---- bf16 MFMA GEMM: BK=64, 2 LDS buffers (64KB, 2 blocks/CU), planar A, scalar epilogue ----
__global__ __launch_bounds__(512) void k_gemm_bf16(const unsigned short* __restrict__ A1,
                                                   const unsigned short* __restrict__ A2,
                                                   const unsigned short* __restrict__ Wt,
                                                   const float* __restrict__ bias,
                                                   unsigned short* __restrict__ OUT, int Nw, int m0,
                                                   int nbx) {
    __shared__ short As[2][8192];   // [buf][128 rows][64 k] = 32KB
    __shared__ short Bs[2][8192];   // [buf][128 cols][64 k] = 32KB
    int bid = blockIdx.x;
    int h = bid & 7;
    int rest = bid >> 3;
    int bx = rest % nbx;
    int by = rest / nbx;
    int t0 = threadIdx.x;
    int lane = t0 & 63, wid = t0 >> 6;      // wid 0..7
    int wr = wid >> 1, wc = wid & 1;        // 32-row x 64-col sub-tile
    int l15 = lane & 15, l4 = lane >> 4;
    int lr = lane >> 3, lc = lane & 7;      // stage decomposition: 8 rows x 8 slots
    const int bxc = bx * 128;
    const size_t mbase = (size_t)(m0 + by * 128);
    const size_t aplane = (size_t)h * 16384;

    float4v acc[2][4];
#pragma unroll
    for (int i = 0; i < 2; ++i)
#pragma unroll
        for (int j = 0; j < 4; ++j) acc[i][j] = (float4v)(0.f);

    auto STAGE = [&](int t, int buf) {
        const unsigned short* src = (t < 2) ? A1 : A2;
        int kofs = (t & 1) * 64;
#pragma unroll
        for (int it = 0; it < 2; ++it) {
            int r0 = wid * 16 + it * 8;
            int r = r0 + lr;
            int c = lc ^ (r & 7);
            size_t g = (aplane + mbase + r) * 128 + kofs + c * 8;   // PLANAR A
            __builtin_amdgcn_global_load_lds((const __attribute__((address_space(1))) void*)(src + g),
                                             (__attribute__((address_space(3))) void*)(&As[buf][r0 * 64]),
                                             16, 0, 0);
        }
#pragma unroll
        for (int it = 0; it < 2; ++it) {
            int n0 = wid * 16 + it * 8;
            int cl = n0 + lr;
            int c = lc ^ (cl & 7);
            size_t g = ((size_t)(h * Nw + bxc + cl)) * 256 + t * 64 + c * 8;
            __builtin_amdgcn_global_load_lds((const __attribute__((address_space(1))) void*)(Wt + g),
                                             (__attribute__((address_space(3))) void*)(&Bs[buf][n0 * 64]),
                                             16, 0, 0);
        }
    };

    STAGE(0, 0);
#pragma unroll
    for (int t = 0; t < 4; ++t) {
        int cur = t & 1;
        if (t < 3) {
            STAGE(t + 1, cur ^ 1);
            asm volatile("s_waitcnt vmcnt(4)" ::: "memory");
        } else {
            asm volatile("s_waitcnt vmcnt(0)" ::: "memory");
        }
        __builtin_amdgcn_s_barrier();
        __builtin_amdgcn_sched_barrier(0);
#pragma unroll
        for (int kk = 0; kk < 2; ++kk) {
            short8v a[2], b[4];
#pragma unroll
            for (int i = 0; i < 2; ++i) {
                int r = wr * 32 + i * 16 + l15;
                int slot = (kk * 4 + l4) ^ (r & 7);
                a[i] = *(const short8v*)(&As[cur][r * 64 + slot * 8]);
            }
#pragma unroll
            for (int j = 0; j < 4; ++j) {
                int c = wc * 64 + j * 16 + l15;
                int slot = (kk * 4 + l4) ^ (c & 7);
                b[j] = *(const short8v*)(&Bs[cur][c * 64 + slot * 8]);
            }
#pragma unroll
            for (int i = 0; i < 2; ++i)
#pragma unroll
                for (int j = 0; j < 4; ++j)
                    acc[i][j] = __builtin_amdgcn_mfma_f32_16x16x32_bf16(a[i], b[j], acc[i][j], 0, 0, 0);
        }
        __builtin_amdgcn_sched_barrier(0);
        __builtin_amdgcn_s_barrier();
    }
#pragma unroll
    for (int j = 0; j < 4; ++j) {
        int o = bxc + wc * 64 + j * 16 + l15;
        float bv = bias[h * Nw + o];
#pragma unroll
        for (int i = 0; i < 2; ++i) {
            int mlb = by * 128 + wr * 32 + i * 16 + l4 * 4;
#pragma unroll
            for (int q = 0; q < 4; ++q) {
                OUT[((size_t)(mlb + q) * 8 + h) * Nw + o] = f2bf(acc[i][j][q] + bv);
            }
        }
    }
}

// ---- FUSED: LN over (h,3,d) + gates + chunk-scan products ----
// One block per 64-row scan chunk. Walks rows j=0..63; per row computes LN+gates
// (writes FG/IG, interleaved, bit-identical to r20), accumulates per-channel
// (F,C) chain from the bf16-ROUNDED gates; writes cF/cC at the end.
__global__ __launch_bounds__(256) void k_ln_gates_scan(const unsigned short* __restrict__ HID,
                                                       unsigned short* __restrict__ FG,
                                                       unsigned short* __restrict__ IG,
                                                       float* __restrict__ cF, float* __restrict__ cC,
                                                       const float* __restrict__ g,
                                                       const float* __restrict__ bb, int m0) {
    __shared__ float sm[3072];
    int t = threadIdx.x;
    int bs0 = m0 + blockIdx.x * 64;          // first row of this scan chunk
    int b = bs0 >> 12;
    int kch = (bs0 & 4095) >> 6;
    int u0 = t * 4;
    int h = u0 >> 7;
    int d0 = u0 & 127;
    float F[4] = {1.f, 1.f, 1.f, 1.f};
    float C[4] = {0.f, 0.f, 0.f, 0.f};

    for (int j = 0; j < 64; ++j) {
        int bs = bs0 + j;
        int bsl = bs - m0;
        const uint4* row = (const uint4*)(HID + (size_t)bsl * 3072);
        float s = 0.f, ss = 0.f;
        for (int idx = t; idx < 384; idx += 256) {
            uint4 u = row[idx];
            float f0 = bf2f_lo(u.x), f1 = bf2f_hi(u.x);
            float f2 = bf2f_lo(u.y), f3 = bf2f_hi(u.y);
            float f4 = bf2f_lo(u.z), f5 = bf2f_hi(u.z);
            float f6 = bf2f_lo(u.w), f7 = bf2f_hi(u.w);
            float* p = sm + idx * 8;
            p[0] = f0; p[1] = f1; p[2] = f2; p[3] = f3; p[4] = f4; p[5] = f5; p[6] = f6; p[7] = f7;
            s += f0 + f1 + f2 + f3 + f4 + f5 + f6 + f7;
            ss += f0 * f0 + f1 * f1 + f2 * f2 + f3 * f3 + f4 * f4 + f5 * f5 + f6 * f6 + f7 * f7;
        }
        block_reduce2(s, ss);
        float m = s * (1.f / 3072.f);
        float var = ss * (1.f / 3072.f) - m * m;
        float r = rsqrtf(fmaxf(var, 0.f) + EPSF);
        float fr[4], ir[4];
#pragma unroll
        for (int q = 0; q < 4; ++q) {
            int d = d0 + q;
            float yi = sm[h * 384 + d];
            float yf = sm[h * 384 + 128 + d];
            float yh = sm[h * 384 + 256 + d];
            float ni = (yi - m) * r * g[(h * 3 + 0) * 128 + d] + bb[(h * 3 + 0) * 128 + d];
            float nf = (yf - m) * r * g[(h * 3 + 1) * 128 + d] + bb[(h * 3 + 1) * 128 + d];
            float nh = (yh - m) * r * g[(h * 3 + 2) * 128 + d] + bb[(h * 3 + 2) * 128 + d];
            fr[q] = sigm(nf);
            ir[q] = sigm(ni) * fmaxf(nh, 0.f);
        }
        uint2 fo, io;
        fo.x = pack2bf(fr[0], fr[1]); fo.y = pack2bf(fr[2], fr[3]);
        io.x = pack2bf(ir[0], ir[1]); io.y = pack2bf(ir[2], ir[3]);
        ((uint2*)(FG + (size_t)bs * 1024))[t] = fo;
        ((uint2*)(IG + (size_t)bs * 1024))[t] = io;
        // chain update from the ROUNDED (written) values -> bit-identical to r20 scan_a
        float fq0 = bf2f_lo(fo.x), fq1 = bf2f_hi(fo.x), fq2 = bf2f_lo(fo.y), fq3 = bf2f_hi(fo.y);
        float iq0 = bf2f_lo(io.x), iq1 = bf2f_hi(io.x), iq2 = bf2f_lo(io.y), iq3 = bf2f_hi(io.y);
        C[0] = fmaf(fq0, C[0], iq0); F[0] *= fq0;
        C[1] = fmaf(fq1, C[1], iq1); F[1] *= fq1;
        C[2] = fmaf(fq2, C[2], iq2); F[2] *= fq2;
        C[3] = fmaf(fq3, C[3], iq3); F[3] *= fq3;
        __syncthreads();   // sm consumed; safe for next row's writes
    }
#pragma unroll
    for (int q = 0; q < 4; ++q) {
        size_t ci = ((size_t)((b * 8 + h) * 128 + d0 + q)) * 64 + kch;
        cF[ci] = F[q];
        cC[ci] = C[q];
    }
}

// per-channel chunk scan: one wave per channel, shfl pair-composition
__global__ __launch_bounds__(256) void k_scan_b(const float* __restrict__ cF, const float* __restrict__ cC,
                                                const float* __restrict__ initcx, float* __restrict__ cI) {
    int wave = (blockIdx.x * 256 + threadIdx.x) >> 6;   // 4096 waves
    int lane = threadIdx.x & 63;
    size_t idx = (size_t)wave * 64 + lane;
    float F = cF[idx], C = cC[idx];
#pragma unroll
    for (int d = 1; d < 64; d <<= 1) {
        float Fp = __shfl_up(F, d);
        float Cp = __shfl_up(C, d);
        if (lane >= d) { C = fmaf(Cp, F, C); F *= Fp; }
    }
    float Fe = __shfl_up(F, 1);
    float Ce = __shfl_up(C, 1);
    if (lane == 0) { Fe = 1.f; Ce = 0.f; }
    float c0 = initcx[wave & 1023];
    cI[idx] = fmaf(Fe, c0, Ce);
}

// final pass: cell -> CLB (planar bf16)
__global__ __launch_bounds__(256) void k_scan_c(const unsigned short* __restrict__ FG,
                                                const unsigned short* __restrict__ IG,
                                                unsigned short* __restrict__ CLB,
                                                const float* __restrict__ cI) {
    int t = blockIdx.x * 256 + threadIdx.x;    // 131072
    int d2 = t & 63, h = (t >> 6) & 7, k = (t >> 9) & 63, b = t >> 15;
    size_t base = (((size_t)(b * 4096 + k * 64)) * 8 + h) * 64 + d2;            // interleaved uint idx
    size_t pbase = ((size_t)h * 16384 + b * 4096 + k * 64) * 64 + d2;           // planar uint idx
    const unsigned int* FGu = (const unsigned int*)FG;
    const unsigned int* IGu = (const unsigned int*)IG;
    unsigned int* CLu = (unsigned int*)CLB;
    size_t ci0 = ((size_t)((b * 8 + h) * 128 + d2 * 2)) * 64 + k;
    float c0 = cI[ci0], c1 = cI[ci0 + 64];
    for (int j = 0; j < 64; ++j) {
        unsigned int fg = FGu[base + (size_t)j * 512];
        unsigned int ig = IGu[base + (size_t)j * 512];
        c0 = fmaf(bf2f_lo(fg), c0, bf2f_lo(ig));
        c1 = fmaf(bf2f_hi(fg), c1, bf2f_hi(ig));
        CLu[pbase + (size_t)j * 64] = pack2bf(c0, c1);
    }
}

// ---- final LN over (h,d) + sigmoid*cell -> out; OG interleaved chunk-local, CLB planar ----
__global__ __launch_bounds__(256) void k_ln_out(const unsigned short* __restrict__ OG,
                                                const unsigned short* __restrict__ CLB,
                                                const float* __restrict__ g, const float* __restrict__ bb,
                                                float* __restrict__ OUT, int m0) {
    int bsl = blockIdx.x, t = threadIdx.x;
    int bs = m0 + bsl;
    uint2 u = ((const uint2*)(OG + (size_t)bsl * 1024))[t];
    float4 v;
    v.x = bf2f_lo(u.x); v.y = bf2f_hi(u.x);
    v.z = bf2f_lo(u.y); v.w = bf2f_hi(u.y);
    float s = v.x + v.y + v.z + v.w;
    float ss = v.x * v.x + v.y * v.y + v.z * v.z + v.w * v.w;
    block_reduce2(s, ss);
    float m = s * (1.f / 1024.f);
    float var = ss * (1.f / 1024.f) - m * m;
    float r = rsqrtf(fmaxf(var, 0.f) + EPSF);
    float4 gv = ((const float4*)g)[t];
    float4 bv = ((const float4*)bb)[t];
    int h = t >> 5, c = t & 31;
    uint2 cu = ((const uint2*)CLB)[((size_t)h * 16384 + bs) * 32 + c];
    float4 cv;
    cv.x = bf2f_lo(cu.x); cv.y = bf2f_hi(cu.x);
    cv.z = bf2f_lo(cu.y); cv.w = bf2f_hi(cu.y);
    float4 o;
    o.x = sigm((v.x - m) * r * gv.x + bv.x) * cv.x;
    o.y = sigm((v.y - m) * r * gv.y + bv.y) * cv.y;
    o.z = sigm((v.z - m) * r * gv.z + bv.z) * cv.z;
    o.w = sigm((v.w - m) * r * gv.w + bv.w) * cv.w;
    ((float4*)(OUT + (size_t)bs * 1024))[t] = o;
}

extern "C" void kernel_launch(void* const* d_in, const int* in_sizes, int n_in,
                              void* d_out, int out_size, void* d_ws, size_t ws_size,
                              hipStream_t stream) {
    const float* X      = (const float*)d_in[0];
    const float* W_hid  = (const float*)d_in[1];
    const float* b_hid  = (const float*)d_in[2];
    const float* W_og   = (const float*)d_in[3];
    const float* b_og   = (const float*)d_in[4];
    const float* g_cs   = (const float*)d_in[5];
    const float* b_cs   = (const float*)d_in[6];
    const float* g_hid  = (const float*)d_in[7];
    const float* b_hidl = (const float*)d_in[8];
    const float* g_og   = (const float*)d_in[9];
    const float* b_ogl  = (const float*)d_in[10];
    const float* initcx = (const float*)d_in[11];

    float* ws = (float*)d_ws;
    const size_t O_SC    = 0ull;           // cS,cO,cF,cC,cI: 5 x 262,144 f32
    const size_t O_XB    = 1310720ull;     // XB bf16 planar (16,777,216 elems)
    const size_t O_CSUMB = 9699328ull;     // CSUMB bf16 planar; aliased as FGB after ln_csum
    const size_t O_CSB   = 18087936ull;    // CSB bf16 planar
    const size_t O_IGB   = 26476544ull;    // IGB bf16 interleaved
    const size_t O_CLB   = 34865152ull;    // CLB bf16 planar
    const size_t O_WTH   = 43253760ull;    // Wt_hid bf16 (786,432 elems)
    const size_t O_WTO   = 43646976ull;    // Wt_og bf16 (262,144 elems)
    const size_t O_HID   = 43778048ull;    // HIDC bf16 chunk buffer (CH*1536 floats)

    float* cS = ws + O_SC;
    float* cO = cS + 262144;
    float* cF = cO + 262144;
    float* cC = cF + 262144;
    float* cI = cC + 262144;
    unsigned short* XB    = (unsigned short*)(ws + O_XB);
    unsigned short* CSUMB = (unsigned short*)(ws + O_CSUMB);
    unsigned short* FGB   = CSUMB;          // alias: CSUMB dead after ln_csum
    unsigned short* CSB   = (unsigned short*)(ws + O_CSB);
    unsigned short* IGB   = (unsigned short*)(ws + O_IGB);
    unsigned short* CLB   = (unsigned short*)(ws + O_CLB);
    unsigned short* WTH   = (unsigned short*)(ws + O_WTH);
    unsigned short* WTO   = (unsigned short*)(ws + O_WTO);
    unsigned short* HIDC  = (unsigned short*)(ws + O_HID);

    size_t avail = (ws_size / 4 > O_HID) ? ws_size / 4 - O_HID : 0;
    int CH = 1024;
    for (int c = 16384; c >= 1024; c >>= 1) {
        if ((size_t)c * 1536ull <= avail) { CH = c; break; }
    }
    const int NC = 16384 / CH;

    dim3 blk(256);
    dim3 blkg(512);
    k_prep_w<<<4096, blk, 0, stream>>>(W_hid, W_og, WTH, WTO);
    k_cumsum_a<<<1024, blk, 0, stream>>>(X, cS, XB);
    k_cumsum_b<<<1024, blk, 0, stream>>>(cS, cO);
    k_cumsum_c<<<1024, blk, 0, stream>>>(XB, cO, CSUMB);
    k_ln_csum<<<16384, blk, 0, stream>>>(CSUMB, CSB, g_cs, b_cs);
    for (int c = 0; c < NC; ++c) {
        int m0 = c * CH;
        k_gemm_bf16<<<8 * 3 * (CH / 128), blkg, 0, stream>>>(XB, CSB, WTH, b_hid, HIDC, 384, m0, 3);
        k_ln_gates_scan<<<CH / 64, blk, 0, stream>>>(HIDC, FGB, IGB, cF, cC, g_hid, b_hidl, m0);
    }
    k_scan_b<<<1024, blk, 0, stream>>>(cF, cC, initcx, cI);
    k_scan_c<<<512, blk, 0, stream>>>(FGB, IGB, CLB, cI);
    for (int c = 0; c < NC; ++c) {
        int m0 = c * CH;
        k_gemm_bf16<<<8 * 1 * (CH / 128), blkg, 0, stream>>>(XB, CLB, WTO, b_og, HIDC, 128, m0, 1);
        k_ln_out<<<CH, blk, 0, stream>>>(HIDC, CLB, g_og, b_ogl, (float*)d_out, m0);
    }
}

// Round 22
// 237.559 us; speedup vs baseline: 1.5841x; 1.5841x over previous
//
#include <hip/hip_runtime.h>

#define EPSF 1e-6f

// Shapes: B=4, S=4096, H=8, D=128;  BS = 16384 rows; channels = 4096
// r20-proven state (237.7 us): A-operands planar [h][bs][d]; GEMM BK=64 double-buffered
// (64KB LDS -> 2 blocks/CU), counted vmcnt(4), raw barriers, planar A staging, scalar
// epilogue to interleaved OUT; separate ln_gates (16384 blocks) + scan_a (512 blocks).
// XCD-pinned heads (h=bid&7).

typedef __attribute__((ext_vector_type(8))) short short8v;
typedef __attribute__((ext_vector_type(4))) float float4v;

__device__ __forceinline__ float sigm(float x) { return 1.0f / (1.0f + __expf(-x)); }

__device__ __forceinline__ unsigned short f2bf(float f) {
    unsigned int u = __float_as_uint(f);
    u = (u + 0x7fffu + ((u >> 16) & 1u)) >> 16;   // RNE
    return (unsigned short)u;
}
__device__ __forceinline__ float bf2f(unsigned short s) { return __uint_as_float(((unsigned int)s) << 16); }
__device__ __forceinline__ float bf2f_lo(unsigned int p) { return __uint_as_float(p << 16); }
__device__ __forceinline__ float bf2f_hi(unsigned int p) { return __uint_as_float(p & 0xffff0000u); }
__device__ __forceinline__ unsigned int pack2bf(float a, float b) {
    return (unsigned int)f2bf(a) | ((unsigned int)f2bf(b) << 16);
}

__device__ __forceinline__ void block_reduce2(float& a, float& b) {
#pragma unroll
    for (int off = 32; off > 0; off >>= 1) {
        a += __shfl_down(a, off);
        b += __shfl_down(b, off);
    }
    __shared__ float sa[8], sb[8];
    int wid = threadIdx.x >> 6;
    int lane = threadIdx.x & 63;
    if (lane == 0) { sa[wid] = a; sb[wid] = b; }
    __syncthreads();
    a = sa[0] + sa[1] + sa[2] + sa[3];
    b = sb[0] + sb[1] + sb[2] + sb[3];
}

// ---- W transpose+cast for BOTH weights in one launch ----
__global__ __launch_bounds__(256) void k_prep_w(const float* __restrict__ Wh, const float* __restrict__ Wo,
                                                unsigned short* __restrict__ WTH,
                                                unsigned short* __restrict__ WTO) {
    int idx = blockIdx.x * 256 + threadIdx.x;    // 1,048,576 total
    if (idx < 786432) {
        int k = idx & 255;
        int rest = idx >> 8;                      // h*384 + o
        int o = rest % 384;
        int h = rest / 384;
        WTH[idx] = f2bf(Wh[((size_t)h * 256 + k) * 384 + o]);
    } else {
        int i2 = idx - 786432;
        int k = i2 & 255;
        int rest = i2 >> 8;                       // h*128 + o
        int o = rest & 127;
        int h = rest >> 7;
        WTO[i2] = f2bf(Wo[((size_t)h * 256 + k) * 128 + o]);
    }
}

// ---- cumsum pass A: chunk sums + emit XB (planar [h][bs][d]) ----
__global__ __launch_bounds__(256) void k_cumsum_a(const float* __restrict__ X, float* __restrict__ cS,
                                                  unsigned short* __restrict__ XB) {
    int t = blockIdx.x * 256 + threadIdx.x;          // 262144
    int d = t & 127, h = (t >> 7) & 7, k = (t >> 10) & 63, b = t >> 16;
    size_t xbase = (((size_t)(b * 4096 + k * 64)) * 8 + h) * 128 + d;          // X interleaved
    size_t pbase = ((size_t)h * 16384 + b * 4096 + k * 64) * 128 + d;           // XB planar
    float s = 0.f;
    for (int j = 0; j < 64; ++j) {
        unsigned short xb = f2bf(X[xbase + (size_t)j * 1024]);
        XB[pbase + (size_t)j * 128] = xb;
        s += bf2f(xb);
    }
    cS[(size_t)((b * 8 + h) * 128 + d) * 64 + k] = s;
}

// pass B: per-channel exclusive scan of chunk sums; one wave per channel
__global__ __launch_bounds__(256) void k_cumsum_b(const float* __restrict__ cS, float* __restrict__ cO) {
    int wave = (blockIdx.x * 256 + threadIdx.x) >> 6;   // 4096 waves
    int lane = threadIdx.x & 63;
    size_t idx = (size_t)wave * 64 + lane;
    float v = cS[idx];
    float incl = v;
#pragma unroll
    for (int d = 1; d < 64; d <<= 1) {
        float t = __shfl_up(incl, d);
        if (lane >= d) incl += t;
    }
    cO[idx] = incl - v;
}

// pass C: exclusive prefix from XB (planar), stored bf16 planar
__global__ __launch_bounds__(256) void k_cumsum_c(const unsigned short* __restrict__ XB,
                                                  const float* __restrict__ cO,
                                                  unsigned short* __restrict__ CSUMB) {
    int t = blockIdx.x * 256 + threadIdx.x;
    int d = t & 127, h = (t >> 7) & 7, k = (t >> 10) & 63, b = t >> 16;
    int ch = (b * 8 + h) * 128 + d;
    float run = cO[(size_t)ch * 64 + k];
    size_t pbase = ((size_t)h * 16384 + b * 4096 + k * 64) * 128 + d;
    for (int j = 0; j < 64; ++j) {
        float x = bf2f(XB[pbase + (size_t)j * 128]);
        CSUMB[pbase + (size_t)j * 128] = f2bf(run);
        run += x;
    }
}

// ---- LN over (h,d) per (b,s): planar bf16 in, planar bf16 out ----
__global__ __launch_bounds__(256) void k_ln_csum(const unsigned short* __restrict__ CSUMB,
                                                 unsigned short* __restrict__ CSB,
                                                 const float* __restrict__ g, const float* __restrict__ bb) {
    int bs = blockIdx.x, t = threadIdx.x;
    int h = t >> 5, c = t & 31;
    size_t u2i = ((size_t)h * 16384 + bs) * 32 + c;    // uint2 index into planar array
    uint2 u = ((const uint2*)CSUMB)[u2i];
    float4 v;
    v.x = bf2f_lo(u.x); v.y = bf2f_hi(u.x);
    v.z = bf2f_lo(u.y); v.w = bf2f_hi(u.y);
    float s = v.x + v.y + v.z + v.w;
    float ss = v.x * v.x + v.y * v.y + v.z * v.z + v.w * v.w;
    block_reduce2(s, ss);
    float m = s * (1.f / 1024.f);
    float var = ss * (1.f / 1024.f) - m * m;
    float r = rsqrtf(fmaxf(var, 0.f) + EPSF);
    float4 gv = ((const float4*)g)[t];
    float4 bv = ((const float4*)bb)[t];
    uint2 o;
    o.x = pack2bf((v.x - m) * r * gv.x + bv.x, (v.y - m) * r * gv.y + bv.y);
    o.y = pack2bf((v.z - m) * r * gv.z + bv.z, (v.w - m) * r * gv.w + bv.w);
    ((uint2*)CSB)[u2i] = o;
}

// ---- bf16 MFMA GEMM: BK=64, 2 LDS buffers (64KB, 2 blocks/CU), planar A, scalar epilogue ----
// Flat grid: h = bid&7, rest = bid>>3, bx = rest%nbx, by = rest/nbx.
// K-steps t=0..3: t<2 reads A1 (kofs=(t&1)*64), t>=2 reads A2; B k-slice = t*64.
// LDS row = 64 bf16 = 8 slots of 16B; slot s of row r holds k-chunk (s ^ (r&7)).
__global__ __launch_bounds__(512) void k_gemm_bf16(const unsigned short* __restrict__ A1,
                                                   const unsigned short* __restrict__ A2,
                                                   const unsigned short* __restrict__ Wt,
                                                   const float* __restrict__ bias,
                                                   unsigned short* __restrict__ OUT, int Nw, int m0,
                                                   int nbx) {
    __shared__ short As[2][8192];   // [buf][128 rows][64 k] = 32KB
    __shared__ short Bs[2][8192];   // [buf][128 cols][64 k] = 32KB
    int bid = blockIdx.x;
    int h = bid & 7;
    int rest = bid >> 3;
    int bx = rest % nbx;
    int by = rest / nbx;
    int t0 = threadIdx.x;
    int lane = t0 & 63, wid = t0 >> 6;      // wid 0..7
    int wr = wid >> 1, wc = wid & 1;        // 32-row x 64-col sub-tile
    int l15 = lane & 15, l4 = lane >> 4;
    int lr = lane >> 3, lc = lane & 7;      // stage decomposition: 8 rows x 8 slots
    const int bxc = bx * 128;
    const size_t mbase = (size_t)(m0 + by * 128);
    const size_t aplane = (size_t)h * 16384;   // planar plane base (rows)

    float4v acc[2][4];
#pragma unroll
    for (int i = 0; i < 2; ++i)
#pragma unroll
        for (int j = 0; j < 4; ++j) acc[i][j] = (float4v)(0.f);

    // stage K-step t into buffer buf: per wave 2 A-issues + 2 B-issues (1KB each)
    auto STAGE = [&](int t, int buf) {
        const unsigned short* src = (t < 2) ? A1 : A2;
        int kofs = (t & 1) * 64;
#pragma unroll
        for (int it = 0; it < 2; ++it) {
            int r0 = wid * 16 + it * 8;
            int r = r0 + lr;
            int c = lc ^ (r & 7);
            size_t g = (aplane + mbase + r) * 128 + kofs + c * 8;   // PLANAR A
            __builtin_amdgcn_global_load_lds((const __attribute__((address_space(1))) void*)(src + g),
                                             (__attribute__((address_space(3))) void*)(&As[buf][r0 * 64]),
                                             16, 0, 0);
        }
#pragma unroll
        for (int it = 0; it < 2; ++it) {
            int n0 = wid * 16 + it * 8;
            int cl = n0 + lr;
            int c = lc ^ (cl & 7);
            size_t g = ((size_t)(h * Nw + bxc + cl)) * 256 + t * 64 + c * 8;
            __builtin_amdgcn_global_load_lds((const __attribute__((address_space(1))) void*)(Wt + g),
                                             (__attribute__((address_space(3))) void*)(&Bs[buf][n0 * 64]),
                                             16, 0, 0);
        }
    };

    STAGE(0, 0);
#pragma unroll
    for (int t = 0; t < 4; ++t) {
        int cur = t & 1;
        if (t < 3) {
            STAGE(t + 1, cur ^ 1);
            asm volatile("s_waitcnt vmcnt(4)" ::: "memory");   // drain step-t's 4 issues; keep t+1's in flight
        } else {
            asm volatile("s_waitcnt vmcnt(0)" ::: "memory");
        }
        __builtin_amdgcn_s_barrier();
        __builtin_amdgcn_sched_barrier(0);
#pragma unroll
        for (int kk = 0; kk < 2; ++kk) {
            short8v a[2], b[4];
#pragma unroll
            for (int i = 0; i < 2; ++i) {
                int r = wr * 32 + i * 16 + l15;
                int slot = (kk * 4 + l4) ^ (r & 7);
                a[i] = *(const short8v*)(&As[cur][r * 64 + slot * 8]);
            }
#pragma unroll
            for (int j = 0; j < 4; ++j) {
                int c = wc * 64 + j * 16 + l15;
                int slot = (kk * 4 + l4) ^ (c & 7);
                b[j] = *(const short8v*)(&Bs[cur][c * 64 + slot * 8]);
            }
#pragma unroll
            for (int i = 0; i < 2; ++i)
#pragma unroll
                for (int j = 0; j < 4; ++j)
                    acc[i][j] = __builtin_amdgcn_mfma_f32_16x16x32_bf16(a[i], b[j], acc[i][j], 0, 0, 0);
        }
        __builtin_amdgcn_sched_barrier(0);
        __builtin_amdgcn_s_barrier();   // all reads of buf[cur] done before STAGE(t+2) overwrites it
    }
    // epilogue: C/D col = lane&15, row = (lane>>4)*4 + q; OUT chunk-local interleaved
#pragma unroll
    for (int j = 0; j < 4; ++j) {
        int o = bxc + wc * 64 + j * 16 + l15;
        float bv = bias[h * Nw + o];
#pragma unroll
        for (int i = 0; i < 2; ++i) {
            int mlb = by * 128 + wr * 32 + i * 16 + l4 * 4;
#pragma unroll
            for (int q = 0; q < 4; ++q) {
                OUT[((size_t)(mlb + q) * 8 + h) * Nw + o] = f2bf(acc[i][j][q] + bv);
            }
        }
    }
}

// ---- LN over (h,3,d) + gates; HID bf16 interleaved chunk-local; FG/IG bf16 interleaved ----
__global__ __launch_bounds__(256) void k_ln_gates(const unsigned short* __restrict__ HID,
                                                  unsigned short* __restrict__ FG,
                                                  unsigned short* __restrict__ IG,
                                                  const float* __restrict__ g, const float* __restrict__ bb,
                                                  int m0) {
    __shared__ float sm[3072];
    int bsl = blockIdx.x, t = threadIdx.x;
    int bs = m0 + bsl;
    const uint4* row = (const uint4*)(HID + (size_t)bsl * 3072);
    float s = 0.f, ss = 0.f;
    for (int idx = t; idx < 384; idx += 256) {
        uint4 u = row[idx];
        float f0 = bf2f_lo(u.x), f1 = bf2f_hi(u.x);
        float f2 = bf2f_lo(u.y), f3 = bf2f_hi(u.y);
        float f4 = bf2f_lo(u.z), f5 = bf2f_hi(u.z);
        float f6 = bf2f_lo(u.w), f7 = bf2f_hi(u.w);
        float* p = sm + idx * 8;
        p[0] = f0; p[1] = f1; p[2] = f2; p[3] = f3; p[4] = f4; p[5] = f5; p[6] = f6; p[7] = f7;
        s += f0 + f1 + f2 + f3 + f4 + f5 + f6 + f7;
        ss += f0 * f0 + f1 * f1 + f2 * f2 + f3 * f3 + f4 * f4 + f5 * f5 + f6 * f6 + f7 * f7;
    }
    block_reduce2(s, ss);
    float m = s * (1.f / 3072.f);
    float var = ss * (1.f / 3072.f) - m * m;
    float r = rsqrtf(fmaxf(var, 0.f) + EPSF);
    int u0 = t * 4;
    int h = u0 >> 7;
    int d0 = u0 & 127;
    float fr[4], ir[4];
#pragma unroll
    for (int q = 0; q < 4; ++q) {
        int d = d0 + q;
        float yi = sm[h * 384 + d];
        float yf = sm[h * 384 + 128 + d];
        float yh = sm[h * 384 + 256 + d];
        float ni = (yi - m) * r * g[(h * 3 + 0) * 128 + d] + bb[(h * 3 + 0) * 128 + d];
        float nf = (yf - m) * r * g[(h * 3 + 1) * 128 + d] + bb[(h * 3 + 1) * 128 + d];
        float nh = (yh - m) * r * g[(h * 3 + 2) * 128 + d] + bb[(h * 3 + 2) * 128 + d];
        fr[q] = sigm(nf);
        ir[q] = sigm(ni) * fmaxf(nh, 0.f);
    }
    uint2 fo, io;
    fo.x = pack2bf(fr[0], fr[1]); fo.y = pack2bf(fr[2], fr[3]);
    io.x = pack2bf(ir[0], ir[1]); io.y = pack2bf(ir[2], ir[3]);
    ((uint2*)(FG + (size_t)bs * 1024))[t] = fo;
    ((uint2*)(IG + (size_t)bs * 1024))[t] = io;
}

// ---- LSTM scan over bf16 gates (interleaved); 2 channels per thread ----
__global__ __launch_bounds__(256) void k_scan_a(const unsigned short* __restrict__ FG,
                                                const unsigned short* __restrict__ IG,
                                                float* __restrict__ cF, float* __restrict__ cC) {
    int t = blockIdx.x * 256 + threadIdx.x;    // 131072
    int d2 = t & 63, h = (t >> 6) & 7, k = (t >> 9) & 63, b = t >> 15;
    size_t base = (((size_t)(b * 4096 + k * 64)) * 8 + h) * 64 + d2;   // uint index
    const unsigned int* FGu = (const unsigned int*)FG;
    const unsigned int* IGu = (const unsigned int*)IG;
    float F0 = 1.f, C0 = 0.f, F1 = 1.f, C1 = 0.f;
    for (int j = 0; j < 64; ++j) {
        unsigned int fg = FGu[base + (size_t)j * 512];
        unsigned int ig = IGu[base + (size_t)j * 512];
        float f0 = bf2f_lo(fg), f1 = bf2f_hi(fg);
        C0 = fmaf(f0, C0, bf2f_lo(ig)); F0 *= f0;
        C1 = fmaf(f1, C1, bf2f_hi(ig)); F1 *= f1;
    }
    size_t ci0 = ((size_t)((b * 8 + h) * 128 + d2 * 2)) * 64 + k;
    cF[ci0] = F0; cC[ci0] = C0;
    cF[ci0 + 64] = F1; cC[ci0 + 64] = C1;
}

// per-channel chunk scan: one wave per channel, shfl pair-composition
__global__ __launch_bounds__(256) void k_scan_b(const float* __restrict__ cF, const float* __restrict__ cC,
                                                const float* __restrict__ initcx, float* __restrict__ cI) {
    int wave = (blockIdx.x * 256 + threadIdx.x) >> 6;   // 4096 waves
    int lane = threadIdx.x & 63;
    size_t idx = (size_t)wave * 64 + lane;
    float F = cF[idx], C = cC[idx];
#pragma unroll
    for (int d = 1; d < 64; d <<= 1) {
        float Fp = __shfl_up(F, d);
        float Cp = __shfl_up(C, d);
        if (lane >= d) { C = fmaf(Cp, F, C); F *= Fp; }
    }
    float Fe = __shfl_up(F, 1);
    float Ce = __shfl_up(C, 1);
    if (lane == 0) { Fe = 1.f; Ce = 0.f; }
    float c0 = initcx[wave & 1023];
    cI[idx] = fmaf(Fe, c0, Ce);
}

// final pass: cell -> CLB (planar bf16)
__global__ __launch_bounds__(256) void k_scan_c(const unsigned short* __restrict__ FG,
                                                const unsigned short* __restrict__ IG,
                                                unsigned short* __restrict__ CLB,
                                                const float* __restrict__ cI) {
    int t = blockIdx.x * 256 + threadIdx.x;    // 131072
    int d2 = t & 63, h = (t >> 6) & 7, k = (t >> 9) & 63, b = t >> 15;
    size_t base = (((size_t)(b * 4096 + k * 64)) * 8 + h) * 64 + d2;            // interleaved uint idx
    size_t pbase = ((size_t)h * 16384 + b * 4096 + k * 64) * 64 + d2;           // planar uint idx
    const unsigned int* FGu = (const unsigned int*)FG;
    const unsigned int* IGu = (const unsigned int*)IG;
    unsigned int* CLu = (unsigned int*)CLB;
    size_t ci0 = ((size_t)((b * 8 + h) * 128 + d2 * 2)) * 64 + k;
    float c0 = cI[ci0], c1 = cI[ci0 + 64];
    for (int j = 0; j < 64; ++j) {
        unsigned int fg = FGu[base + (size_t)j * 512];
        unsigned int ig = IGu[base + (size_t)j * 512];
        c0 = fmaf(bf2f_lo(fg), c0, bf2f_lo(ig));
        c1 = fmaf(bf2f_hi(fg), c1, bf2f_hi(ig));
        CLu[pbase + (size_t)j * 64] = pack2bf(c0, c1);
    }
}

// ---- final LN over (h,d) + sigmoid*cell -> out; OG interleaved chunk-local, CLB planar ----
__global__ __launch_bounds__(256) void k_ln_out(const unsigned short* __restrict__ OG,
                                                const unsigned short* __restrict__ CLB,
                                                const float* __restrict__ g, const float* __restrict__ bb,
                                                float* __restrict__ OUT, int m0) {
    int bsl = blockIdx.x, t = threadIdx.x;
    int bs = m0 + bsl;
    uint2 u = ((const uint2*)(OG + (size_t)bsl * 1024))[t];
    float4 v;
    v.x = bf2f_lo(u.x); v.y = bf2f_hi(u.x);
    v.z = bf2f_lo(u.y); v.w = bf2f_hi(u.y);
    float s = v.x + v.y + v.z + v.w;
    float ss = v.x * v.x + v.y * v.y + v.z * v.z + v.w * v.w;
    block_reduce2(s, ss);
    float m = s * (1.f / 1024.f);
    float var = ss * (1.f / 1024.f) - m * m;
    float r = rsqrtf(fmaxf(var, 0.f) + EPSF);
    float4 gv = ((const float4*)g)[t];
    float4 bv = ((const float4*)bb)[t];
    int h = t >> 5, c = t & 31;
    uint2 cu = ((const uint2*)CLB)[((size_t)h * 16384 + bs) * 32 + c];
    float4 cv;
    cv.x = bf2f_lo(cu.x); cv.y = bf2f_hi(cu.x);
    cv.z = bf2f_lo(cu.y); cv.w = bf2f_hi(cu.y);
    float4 o;
    o.x = sigm((v.x - m) * r * gv.x + bv.x) * cv.x;
    o.y = sigm((v.y - m) * r * gv.y + bv.y) * cv.y;
    o.z = sigm((v.z - m) * r * gv.z + bv.z) * cv.z;
    o.w = sigm((v.w - m) * r * gv.w + bv.w) * cv.w;
    ((float4*)(OUT + (size_t)bs * 1024))[t] = o;
}

extern "C" void kernel_launch(void* const* d_in, const int* in_sizes, int n_in,
                              void* d_out, int out_size, void* d_ws, size_t ws_size,
                              hipStream_t stream) {
    const float* X      = (const float*)d_in[0];
    const float* W_hid  = (const float*)d_in[1];
    const float* b_hid  = (const float*)d_in[2];
    const float* W_og   = (const float*)d_in[3];
    const float* b_og   = (const float*)d_in[4];
    const float* g_cs   = (const float*)d_in[5];
    const float* b_cs   = (const float*)d_in[6];
    const float* g_hid  = (const float*)d_in[7];
    const float* b_hidl = (const float*)d_in[8];
    const float* g_og   = (const float*)d_in[9];
    const float* b_ogl  = (const float*)d_in[10];
    const float* initcx = (const float*)d_in[11];

    float* ws = (float*)d_ws;
    const size_t O_SC    = 0ull;           // cS,cO,cF,cC,cI: 5 x 262,144 f32
    const size_t O_XB    = 1310720ull;     // XB bf16 planar (16,777,216 elems)
    const size_t O_CSUMB = 9699328ull;     // CSUMB bf16 planar; aliased as FGB after ln_csum
    const size_t O_CSB   = 18087936ull;    // CSB bf16 planar
    const size_t O_IGB   = 26476544ull;    // IGB bf16 interleaved
    const size_t O_CLB   = 34865152ull;    // CLB bf16 planar
    const size_t O_WTH   = 43253760ull;    // Wt_hid bf16 (786,432 elems)
    const size_t O_WTO   = 43646976ull;    // Wt_og bf16 (262,144 elems)
    const size_t O_HID   = 43778048ull;    // HIDC bf16 chunk buffer (CH*1536 floats)

    float* cS = ws + O_SC;
    float* cO = cS + 262144;
    float* cF = cO + 262144;
    float* cC = cF + 262144;
    float* cI = cC + 262144;
    unsigned short* XB    = (unsigned short*)(ws + O_XB);
    unsigned short* CSUMB = (unsigned short*)(ws + O_CSUMB);
    unsigned short* FGB   = CSUMB;          // alias: CSUMB dead after ln_csum
    unsigned short* CSB   = (unsigned short*)(ws + O_CSB);
    unsigned short* IGB   = (unsigned short*)(ws + O_IGB);
    unsigned short* CLB   = (unsigned short*)(ws + O_CLB);
    unsigned short* WTH   = (unsigned short*)(ws + O_WTH);
    unsigned short* WTO   = (unsigned short*)(ws + O_WTO);
    unsigned short* HIDC  = (unsigned short*)(ws + O_HID);

    size_t avail = (ws_size / 4 > O_HID) ? ws_size / 4 - O_HID : 0;
    int CH = 1024;
    for (int c = 16384; c >= 1024; c >>= 1) {
        if ((size_t)c * 1536ull <= avail) { CH = c; break; }
    }
    const int NC = 16384 / CH;

    dim3 blk(256);
    dim3 blkg(512);
    k_prep_w<<<4096, blk, 0, stream>>>(W_hid, W_og, WTH, WTO);
    k_cumsum_a<<<1024, blk, 0, stream>>>(X, cS, XB);
    k_cumsum_b<<<1024, blk, 0, stream>>>(cS, cO);
    k_cumsum_c<<<1024, blk, 0, stream>>>(XB, cO, CSUMB);
    k_ln_csum<<<16384, blk, 0, stream>>>(CSUMB, CSB, g_cs, b_cs);
    for (int c = 0; c < NC; ++c) {
        int m0 = c * CH;
        k_gemm_bf16<<<8 * 3 * (CH / 128), blkg, 0, stream>>>(XB, CSB, WTH, b_hid, HIDC, 384, m0, 3);
        k_ln_gates<<<CH, blk, 0, stream>>>(HIDC, FGB, IGB, g_hid, b_hidl, m0);
    }
    k_scan_a<<<512, blk, 0, stream>>>(FGB, IGB, cF, cC);
    k_scan_b<<<1024, blk, 0, stream>>>(cF, cC, initcx, cI);
    k_scan_c<<<512, blk, 0, stream>>>(FGB, IGB, CLB, cI);
    for (int c = 0; c < NC; ++c) {
        int m0 = c * CH;
        k_gemm_bf16<<<8 * 1 * (CH / 128), blkg, 0, stream>>>(XB, CLB, WTO, b_og, HIDC, 128, m0, 1);
        k_ln_out<<<CH, blk, 0, stream>>>(HIDC, CLB, g_og, b_ogl, (float*)d_out, m0);
    }
}